// Round 9
// baseline (327.296 us; speedup 1.0000x reference)
//
#include <hip/hip_runtime.h>
#include <math.h>

// ---------------------------------------------------------------------------
// QuadraLayer fused, bf16-MFMA path, round 9 (best-of-each A/B).
// r7 (337us): attn=131us (non-hoisted), mlp_ln~124us (non-hoisted).
// r8 (317us): attn=151us (hoisted, REGRESSED), mlp_ln~84us (hoisted, WIN).
// r9: k_mlp_ln keeps r8 hoisted B-fragment structure; k_attn_mlp MFMA
// phases reverted byte-exact to r7 (measured 131us). Everything else same.
// Also serves as A/B for container-noise: if attn stays ~150 with r7 code,
// r8's regression was noise.
// ---------------------------------------------------------------------------

typedef short short8 __attribute__((ext_vector_type(8)));
typedef short short4v __attribute__((ext_vector_type(4)));
typedef float floatx4 __attribute__((ext_vector_type(4)));

#define MFMA_BF16(a, b, c) __builtin_amdgcn_mfma_f32_16x16x32_bf16((a), (b), (c), 0, 0, 0)

__device__ __forceinline__ short f2b(float f) {
  unsigned u = __builtin_bit_cast(unsigned, f);
  u += 0x7FFFu + ((u >> 16) & 1u);
  return (short)(u >> 16);
}
__device__ __forceinline__ float b2f(short s) {
  unsigned u = ((unsigned)(unsigned short)s) << 16;
  return __builtin_bit_cast(float, u);
}
// gelu(v) = 0.5 v (1+erf(v/sqrt2)); erf via A&S 7.1.26 (|eps|<=1.5e-7)
__device__ __forceinline__ float gelu_fast(float v) {
  float z  = v * 0.70710678118654752f;
  float az = fabsf(z);
  float t  = __builtin_amdgcn_rcpf(1.0f + 0.3275911f * az);
  float poly = ((((1.061405429f * t - 1.453152027f) * t + 1.421413741f) * t
                 - 0.284496736f) * t + 0.254829592f) * t;
  float e = 1.0f - poly * __expf(-az * az);
  float erfv = copysignf(e, z);
  return 0.5f * v * (1.0f + erfv);
}

// ---------------------------------------------------------------------------
// Pack all weights into bf16 MFMA fragments.
// lane -> (free dim = lane&15, k = (lane>>4)*8+j); P[((nt*KS+ks)*64+lane)*8+j]
// ---------------------------------------------------------------------------
__global__ void pack_all(const float* __restrict__ m1w1, const float* __restrict__ m1w2,
                         const float* __restrict__ m2w1, const float* __restrict__ m2w2,
                         const float* __restrict__ wq,
                         const float* __restrict__ wk, const float* __restrict__ wv,
                         const float* __restrict__ wr,
                         short* __restrict__ w1p1, short* __restrict__ w2p1,
                         short* __restrict__ w1p2, short* __restrict__ w2p2,
                         short* __restrict__ wqp, short* __restrict__ wkp,
                         short* __restrict__ wvp, short* __restrict__ wrp) {
  int idx = blockIdx.x * 256 + threadIdx.x;
  const float* W; short* P; int KS, N, base;
  if (idx < 65536)       { W = m1w1; P = w1p1; KS = 4;  N = 512; base = 0; }
  else if (idx < 131072) { W = m1w2; P = w2p1; KS = 16; N = 128; base = 65536; }
  else if (idx < 196608) { W = m2w1; P = w1p2; KS = 4;  N = 512; base = 131072; }
  else if (idx < 262144) { W = m2w2; P = w2p2; KS = 16; N = 128; base = 196608; }
  else if (idx < 278528) { W = wq;   P = wqp;  KS = 4;  N = 128; base = 262144; }
  else if (idx < 294912) { W = wk;   P = wkp;  KS = 4;  N = 128; base = 278528; }
  else if (idx < 311296) { W = wv;   P = wvp;  KS = 4;  N = 128; base = 294912; }
  else if (idx < 327680) { W = wr;   P = wrp;  KS = 4;  N = 128; base = 311296; }
  else return;
  int i = idx - base;
  int j    = i & 7;
  int lane = (i >> 3) & 63;
  int ks   = (i >> 9) % KS;
  int nt   = i / (KS << 9);
  int k = ks * 32 + ((lane >> 4) << 3) + j;
  int n = nt * 16 + (lane & 15);
  P[i] = f2b(W[k * N + n]);
}

// ---------------------------------------------------------------------------
// Stage B: x_proj(bf16) = LN(x + MLP1(x)). 64 rows/block.
// Column-split GEMMs with hoisted B-fragment reads (r8 form, ~84us measured).
// ---------------------------------------------------------------------------
__global__ __launch_bounds__(256, 4)
void k_mlp_ln(const float* __restrict__ X, short* __restrict__ OUTb,
              const short* __restrict__ w1p, const float* __restrict__ b1,
              const short* __restrict__ w2p, const float* __restrict__ b2,
              const float* __restrict__ g, const float* __restrict__ be) {
  __shared__ __align__(16) short xb[64 * 136];
  __shared__ __align__(16) short hb[64 * 136];
  __shared__ float2 st[256];              // [token][wave] partial (s1, s2)

  const int tid  = threadIdx.x;
  const int lane = tid & 63;
  const int wave = tid >> 6;
  const int quad = lane >> 4;
  const int ln16 = lane & 15;
  const long rowbase = (long)blockIdx.x * 64;
  const float* xsrc = X + rowbase * 128;

#pragma unroll
  for (int i = 0; i < 8; ++i) {
    int flat = tid + 256 * i;
    int r  = flat >> 5;
    int c4 = (flat & 31) << 2;
    floatx4 v = *(const floatx4*)(xsrc + r * 128 + c4);
    short4v s;
    s[0] = f2b(v[0]); s[1] = f2b(v[1]); s[2] = f2b(v[2]); s[3] = f2b(v[3]);
    *(short4v*)&xb[r * 136 + c4] = s;
  }
  __syncthreads();

  const int nt0 = wave * 2;          // this wave's GEMM2 output col tiles
  floatx4 acc2[2][4];                // [nt_local][row_tile]
#pragma unroll
  for (int n = 0; n < 2; ++n)
#pragma unroll
    for (int rt = 0; rt < 4; ++rt) acc2[n][rt] = (floatx4){0.f, 0.f, 0.f, 0.f};

#pragma unroll 1
  for (int qtr = 0; qtr < 4; ++qtr) {
    // ---- GEMM1 quarter: h col tiles ntg = qtr*8+nt0+{0,1}, all 64 rows ----
    const int ntgA = qtr * 8 + nt0;
    floatx4 a1[2][4];
#pragma unroll
    for (int n = 0; n < 2; ++n)
#pragma unroll
      for (int rt = 0; rt < 4; ++rt) a1[n][rt] = (floatx4){0.f, 0.f, 0.f, 0.f};
#pragma unroll
    for (int ks = 0; ks < 4; ++ks) {
      short8 bf[4];
#pragma unroll
      for (int rt = 0; rt < 4; ++rt)
        bf[rt] = *(const short8*)&xb[(rt * 16 + ln16) * 136 + ks * 32 + quad * 8];
      short8 af0 = *(const short8*)&w1p[((ntgA * 4 + ks) * 64 + lane) * 8];
      short8 af1 = *(const short8*)&w1p[(((ntgA + 1) * 4 + ks) * 64 + lane) * 8];
#pragma unroll
      for (int rt = 0; rt < 4; ++rt) a1[0][rt] = MFMA_BF16(af0, bf[rt], a1[0][rt]);
#pragma unroll
      for (int rt = 0; rt < 4; ++rt) a1[1][rt] = MFMA_BF16(af1, bf[rt], a1[1][rt]);
    }
#pragma unroll
    for (int n = 0; n < 2; ++n) {
      floatx4 bias = *(const floatx4*)&b1[(ntgA + n) * 16 + quad * 4];
#pragma unroll
      for (int rt = 0; rt < 4; ++rt) {
        short4v hv;
#pragma unroll
        for (int r = 0; r < 4; ++r) hv[r] = f2b(gelu_fast(a1[n][rt][r] + bias[r]));
        *(short4v*)&hb[(rt * 16 + ln16) * 136 + (nt0 + n) * 16 + quad * 4] = hv;
      }
    }
    __syncthreads();
    // ---- GEMM2 quarter: fixed output tiles nt0,nt0+1; K-slice qtr*4+ks ----
#pragma unroll
    for (int ks = 0; ks < 4; ++ks) {
      short8 bf[4];
#pragma unroll
      for (int rt = 0; rt < 4; ++rt)
        bf[rt] = *(const short8*)&hb[(rt * 16 + ln16) * 136 + ks * 32 + quad * 8];
      short8 af0 = *(const short8*)&w2p[((nt0 * 16 + qtr * 4 + ks) * 64 + lane) * 8];
      short8 af1 = *(const short8*)&w2p[(((nt0 + 1) * 16 + qtr * 4 + ks) * 64 + lane) * 8];
#pragma unroll
      for (int rt = 0; rt < 4; ++rt) acc2[0][rt] = MFMA_BF16(af0, bf[rt], acc2[0][rt]);
#pragma unroll
      for (int rt = 0; rt < 4; ++rt) acc2[1][rt] = MFMA_BF16(af1, bf[rt], acc2[1][rt]);
    }
    __syncthreads();
  }

  // residual + bias in-register; per-wave partial LN stats -> st[]
#pragma unroll
  for (int rt = 0; rt < 4; ++rt) {
    float p1 = 0.f, p2 = 0.f;
#pragma unroll
    for (int n = 0; n < 2; ++n) {
      const int col = (nt0 + n) * 16 + quad * 4;
      floatx4 bb = *(const floatx4*)&b2[col];
      floatx4 xres = *(const floatx4*)(xsrc + (rt * 16 + ln16) * 128 + col);
      floatx4 v;
#pragma unroll
      for (int r = 0; r < 4; ++r) {
        v[r] = acc2[n][rt][r] + bb[r] + xres[r];
        p1 += v[r]; p2 += v[r] * v[r];
      }
      acc2[n][rt] = v;
    }
    p1 += __shfl_xor(p1, 16); p1 += __shfl_xor(p1, 32);
    p2 += __shfl_xor(p2, 16); p2 += __shfl_xor(p2, 32);
    if (quad == 0) st[(rt * 16 + ln16) * 4 + wave] = (float2){p1, p2};
  }
  __syncthreads();

  // combine partials; each wave normalizes + writes its own 32 cols per row
#pragma unroll
  for (int rt = 0; rt < 4; ++rt) {
    const int tok = rt * 16 + ln16;
    float s1 = 0.f, s2 = 0.f;
#pragma unroll
    for (int w4 = 0; w4 < 4; ++w4) {
      float2 pp = st[tok * 4 + w4];
      s1 += pp.x; s2 += pp.y;
    }
    const float mean = s1 * (1.0f / 128.0f);
    const float rstd = rsqrtf(s2 * (1.0f / 128.0f) - mean * mean + 1e-5f);
    short* orow = OUTb + (rowbase + tok) * 128;
#pragma unroll
    for (int n = 0; n < 2; ++n) {
      const int col = (nt0 + n) * 16 + quad * 4;
      floatx4 gg = *(const floatx4*)&g[col];
      floatx4 bb = *(const floatx4*)&be[col];
      short4v o;
#pragma unroll
      for (int r = 0; r < 4; ++r)
        o[r] = f2b((acc2[n][rt][r] - mean) * rstd * gg[r] + bb[r]);
      *(short4v*)&orow[col] = o;
    }
  }
}

// ---------------------------------------------------------------------------
// Stage C: K/V (t<15) + router projections via MFMA, then banded attn1.
// One block per (b,l). LDS 23 KB. (unchanged, verified)
// ---------------------------------------------------------------------------
__global__ __launch_bounds__(256, 4)
void k_buffer(const short* __restrict__ XPb, const float* __restrict__ router,
              const short* __restrict__ wkp, const float* __restrict__ b_k,
              const short* __restrict__ wvp, const float* __restrict__ b_v,
              const short* __restrict__ wrp, const float* __restrict__ b_r,
              float* __restrict__ BUF) {
  __shared__ __align__(16) short ab[32 * 136];
  __shared__ __align__(16) short kp[16 * 136];
  __shared__ __align__(16) short vp[16 * 136];
  __shared__ __align__(16) short rp[16 * 136];
  __shared__ float sc[20 * 16];
  const int tid  = threadIdx.x;
  const int lane = tid & 63;
  const int wave = tid >> 6;
  const int quad = lane >> 4;
  const int ln16 = lane & 15;
  const int bl = blockIdx.x;
  const int b = bl >> 5, l = bl & 31;

  if (tid < 240) {
    int r = tid >> 4, c8 = (tid & 15) << 3;
    short8 v = *(const short8*)(XPb + (((long)b * 1024 + r) * 32 + l) * 128 + c8);
    *(short8*)&ab[r * 136 + c8] = v;
  }
  for (int i = tid; i < 320; i += 256) {
    int r = i >> 5, c4 = (i & 31) << 2;
    floatx4 v = *(const floatx4*)(router + (long)l * 1280 + r * 128 + c4);
    short4v s;
    s[0] = f2b(v[0]); s[1] = f2b(v[1]); s[2] = f2b(v[2]); s[3] = f2b(v[3]);
    *(short4v*)&ab[(16 + r) * 136 + c4] = s;
  }
  __syncthreads();

  for (int idx = wave; idx < 24; idx += 4) {
    const int m = idx >> 3, nt = idx & 7;
    const short* wp   = (m == 0) ? wkp : (m == 1) ? wvp : wrp;
    const float* bias = (m == 0) ? b_k : (m == 1) ? b_v : b_r;
    const int abase = (m == 2) ? 16 * 136 : 0;
    floatx4 acc = {0.f, 0.f, 0.f, 0.f};
#pragma unroll
    for (int ks = 0; ks < 4; ++ks) {
      short8 bf = *(const short8*)&ab[abase + ln16 * 136 + ks * 32 + quad * 8];
      short8 af = *(const short8*)&wp[((nt * 4 + ks) * 64 + lane) * 8];
      acc = MFMA_BF16(af, bf, acc);
    }
    floatx4 bb = *(const floatx4*)&bias[nt * 16 + quad * 4];
    short* dst = (m == 0) ? kp : (m == 1) ? vp : rp;
    short4v o;
#pragma unroll
    for (int r = 0; r < 4; ++r) o[r] = f2b(acc[r] + bb[r]);
    *(short4v*)&dst[ln16 * 136 + nt * 16 + quad * 4] = o;
  }
  __syncthreads();

  for (int t = tid; t < 220; t += 256) {
    int pair = t / 11, jrel = t - pair * 11;
    int i = pair >> 1, hd = pair & 1;
    int j = i - 5 + jrel;
    float s;
    if (j < 0) s = -1e30f;
    else {
      float a0 = 0.f, a1 = 0.f;
      for (int d = 0; d < 64; d += 2) {
        a0 += b2f(rp[i * 136 + hd * 64 + d])     * b2f(kp[j * 136 + hd * 64 + d]);
        a1 += b2f(rp[i * 136 + hd * 64 + d + 1]) * b2f(kp[j * 136 + hd * 64 + d + 1]);
      }
      s = fminf(fmaxf((a0 + a1) * 0.125f, -10000.0f), 10000.0f);
    }
    sc[pair * 16 + jrel] = s;
  }
  __syncthreads();
  if (tid < 20) {
    float mx = -1e30f;
    for (int jr = 0; jr < 11; ++jr) mx = fmaxf(mx, sc[tid * 16 + jr]);
    float den = 0.f, e[11];
    for (int jr = 0; jr < 11; ++jr) { e[jr] = __expf(sc[tid * 16 + jr] - mx); den += e[jr]; }
    float rden = 1.0f / den;
    for (int jr = 0; jr < 11; ++jr) sc[tid * 16 + jr] = e[jr] * rden;
  }
  __syncthreads();
  for (int e = tid; e < 1280; e += 256) {
    int pair = e >> 6, d = e & 63;
    int i = pair >> 1, hd = pair & 1;
    float o = 0.f;
#pragma unroll
    for (int jr = 0; jr < 11; ++jr) {
      int j = i - 5 + jr;
      int jc = (j < 0) ? 0 : j;
      o += sc[pair * 16 + jr] * b2f(vp[jc * 136 + hd * 64 + d]);
    }
    BUF[((bl * 2 + hd) * 10 + i) * 64 + d] = o;
  }
}

// ---------------------------------------------------------------------------
// Stage D: q-proj + attn2(10 keys) + MLP2 + LN2 + LN3 -> out.
// MFMA phases in r7 form (measured 131us). Dual-LN via kv[] reuse.
// ---------------------------------------------------------------------------
__global__ __launch_bounds__(256, 4)
void k_attn_mlp(const short* __restrict__ XPb, const float* __restrict__ BUF,
                float* __restrict__ OUT,
                const short* __restrict__ wqp, const float* __restrict__ bq,
                const short* __restrict__ w1p, const float* __restrict__ b1,
                const short* __restrict__ w2p, const float* __restrict__ b2,
                const float* __restrict__ g2, const float* __restrict__ be2,
                const float* __restrict__ g3, const float* __restrict__ be3) {
  __shared__ __align__(16) short xb[64 * 136];
  __shared__ __align__(16) short qh[64 * 136];
  __shared__ __align__(16) float kv[1280];   // K/V buffer; reused as LN partials

  const int tid  = threadIdx.x;
  const int lane = tid & 63;
  const int wave = tid >> 6;
  const int quad = lane >> 4;
  const int ln16 = lane & 15;

  const int bx = blockIdx.x;
  const int bl = bx >> 4;
  const int tt = bx & 15;
  const int b = bl >> 5, l = bl & 31;
  const int t0 = tt * 64;
  const long basef = ((long)(b * 1024 + t0) * 32 + l) * 128;

#pragma unroll
  for (int i = 0; i < 4; ++i) {
    int flat = tid + 256 * i;
    int r  = flat >> 4;
    int c8 = (flat & 15) << 3;
    short8 v = *(const short8*)(XPb + basef + (long)r * 4096 + c8);
    *(short8*)&xb[r * 136 + c8] = v;
  }
  for (int i = tid; i < 1280; i += 256) kv[i] = BUF[bl * 1280 + i];
  __syncthreads();

  const int nt0 = wave * 2;

  // q-proj, column-split (r7 form): wave owns col tiles {2w, 2w+1}
#pragma unroll
  for (int n = 0; n < 2; ++n) {
    const int nt = nt0 + n;
    short8 af[4];
#pragma unroll
    for (int ks = 0; ks < 4; ++ks)
      af[ks] = *(const short8*)&wqp[((nt * 4 + ks) * 64 + lane) * 8];
    floatx4 a1[4];
#pragma unroll
    for (int rt = 0; rt < 4; ++rt) a1[rt] = (floatx4){0.f, 0.f, 0.f, 0.f};
#pragma unroll
    for (int ks = 0; ks < 4; ++ks)
#pragma unroll
      for (int rt = 0; rt < 4; ++rt) {
        short8 bf = *(const short8*)&xb[(rt * 16 + ln16) * 136 + ks * 32 + quad * 8];
        a1[rt] = MFMA_BF16(af[ks], bf, a1[rt]);
      }
    floatx4 bb = *(const floatx4*)&bq[nt * 16 + quad * 4];
#pragma unroll
    for (int rt = 0; rt < 4; ++rt) {
      short4v qv;
#pragma unroll
      for (int r = 0; r < 4; ++r) qv[r] = f2b(a1[rt][r] + bb[r]);
      *(short4v*)&qh[(rt * 16 + ln16) * 136 + nt * 16 + quad * 4] = qv;
    }
  }
  __syncthreads();

  // attn2: 128 threads, one (row, head) each; writes output into xb
  if (tid < 128) {
    const int row = tid >> 1, hd = tid & 1;
    const int t = t0 + row;
    const short* qrow = &qh[row * 136 + hd * 64];
    const float* kvh  = &kv[hd * 640];
    float p[10];
#pragma unroll
    for (int j = 0; j < 10; ++j) p[j] = 0.f;
#pragma unroll
    for (int c = 0; c < 8; ++c) {
      short8 qs = *(const short8*)&qrow[c * 8];
      float qf[8];
#pragma unroll
      for (int u = 0; u < 8; ++u) qf[u] = b2f(qs[u]);
#pragma unroll
      for (int j = 0; j < 10; ++j) {
        const float* kp = &kvh[j * 64 + c * 8];
        floatx4 k0 = *(const floatx4*)kp;
        floatx4 k1 = *(const floatx4*)(kp + 4);
        p[j] += qf[0] * k0[0] + qf[1] * k0[1] + qf[2] * k0[2] + qf[3] * k0[3]
              + qf[4] * k1[0] + qf[5] * k1[1] + qf[6] * k1[2] + qf[7] * k1[3];
      }
    }
    const bool full = (t >= 10);
    const int jlo = t - 5, jhi = t + 5;
    float mx = -1e30f;
#pragma unroll
    for (int j = 0; j < 10; ++j) {
      float s = fminf(fmaxf(p[j] * 0.125f, -10000.0f), 10000.0f);
      s = (full || (j >= jlo && j <= jhi)) ? s : -1e30f;
      p[j] = s; mx = fmaxf(mx, s);
    }
    float den = 0.f;
#pragma unroll
    for (int j = 0; j < 10; ++j) { p[j] = __expf(p[j] - mx); den += p[j]; }
    const float rden = 1.0f / den;
#pragma unroll
    for (int j = 0; j < 10; ++j) p[j] *= rden;
#pragma unroll
    for (int c = 0; c < 16; ++c) {
      floatx4 o = {0.f, 0.f, 0.f, 0.f};
#pragma unroll
      for (int j = 0; j < 10; ++j) {
        floatx4 vv = *(const floatx4*)&kv[hd * 640 + j * 64 + c * 4];
        o += p[j] * vv;
      }
      short4v s;
#pragma unroll
      for (int r = 0; r < 4; ++r) s[r] = f2b(o[r]);
      *(short4v*)&xb[row * 136 + hd * 64 + c * 4] = s;
    }
  }
  __syncthreads();

  // MLP2, column-split (r7 form: af[4] per n, bf read per rt)
  floatx4 acc2[2][4];
#pragma unroll
  for (int n = 0; n < 2; ++n)
#pragma unroll
    for (int rt = 0; rt < 4; ++rt) acc2[n][rt] = (floatx4){0.f, 0.f, 0.f, 0.f};

#pragma unroll 1
  for (int qtr = 0; qtr < 4; ++qtr) {
#pragma unroll
    for (int n = 0; n < 2; ++n) {
      const int ntg = qtr * 8 + nt0 + n;
      short8 af[4];
#pragma unroll
      for (int ks = 0; ks < 4; ++ks)
        af[ks] = *(const short8*)&w1p[((ntg * 4 + ks) * 64 + lane) * 8];
      floatx4 a1[4];
#pragma unroll
      for (int rt = 0; rt < 4; ++rt) a1[rt] = (floatx4){0.f, 0.f, 0.f, 0.f};
#pragma unroll
      for (int ks = 0; ks < 4; ++ks)
#pragma unroll
        for (int rt = 0; rt < 4; ++rt) {
          short8 bf = *(const short8*)&xb[(rt * 16 + ln16) * 136 + ks * 32 + quad * 8];
          a1[rt] = MFMA_BF16(af[ks], bf, a1[rt]);
        }
      floatx4 bias = *(const floatx4*)&b1[ntg * 16 + quad * 4];
#pragma unroll
      for (int rt = 0; rt < 4; ++rt) {
        short4v hv;
#pragma unroll
        for (int r = 0; r < 4; ++r) hv[r] = f2b(gelu_fast(a1[rt][r] + bias[r]));
        *(short4v*)&qh[(rt * 16 + ln16) * 136 + (nt0 + n) * 16 + quad * 4] = hv;
      }
    }
    __syncthreads();
#pragma unroll
    for (int n = 0; n < 2; ++n) {
      const int nt = nt0 + n;
      short8 af[4];
#pragma unroll
      for (int ks = 0; ks < 4; ++ks)
        af[ks] = *(const short8*)&w2p[((nt * 16 + qtr * 4 + ks) * 64 + lane) * 8];
#pragma unroll
      for (int ks = 0; ks < 4; ++ks)
#pragma unroll
        for (int rt = 0; rt < 4; ++rt) {
          short8 bf = *(const short8*)&qh[(rt * 16 + ln16) * 136 + ks * 32 + quad * 8];
          acc2[n][rt] = MFMA_BF16(af[ks], bf, acc2[n][rt]);
        }
    }
    __syncthreads();
  }

  // ---- dual-LN epilogue via kv[] reuse (kv dead after attn phase) ----
  float* st = kv;          // st[0..255]=s1, st[256..511]=s2, [512..767]=z1, [768..1023]=z2
  float mean1r[4], rstd1r[4];

  // round 1: v = acc2 + b2 + residual(XPb); per-wave partials
#pragma unroll
  for (int rt = 0; rt < 4; ++rt) {
    const int tok = rt * 16 + ln16;
    float p1 = 0.f, p2 = 0.f;
#pragma unroll
    for (int n = 0; n < 2; ++n) {
      const int col = (nt0 + n) * 16 + quad * 4;
      floatx4 bb = *(const floatx4*)&b2[col];
      short4v xs4 = *(const short4v*)&XPb[basef + (long)tok * 4096 + col];
      floatx4 v;
#pragma unroll
      for (int r = 0; r < 4; ++r) {
        v[r] = acc2[n][rt][r] + bb[r] + b2f(xs4[r]);
        p1 += v[r]; p2 += v[r] * v[r];
      }
      acc2[n][rt] = v;
    }
    p1 += __shfl_xor(p1, 16); p1 += __shfl_xor(p1, 32);
    p2 += __shfl_xor(p2, 16); p2 += __shfl_xor(p2, 32);
    if (quad == 0) { st[tok * 4 + wave] = p1; st[256 + tok * 4 + wave] = p2; }
  }
  __syncthreads();

  // round 2: combine -> mean1/rstd1; z-partials -> st[512..]
#pragma unroll
  for (int rt = 0; rt < 4; ++rt) {
    const int tok = rt * 16 + ln16;
    float s1 = 0.f, s2 = 0.f;
#pragma unroll
    for (int w4 = 0; w4 < 4; ++w4) { s1 += st[tok * 4 + w4]; s2 += st[256 + tok * 4 + w4]; }
    const float mean1 = s1 * (1.0f / 128.0f);
    const float rstd1 = rsqrtf(s2 * (1.0f / 128.0f) - mean1 * mean1 + 1e-5f);
    mean1r[rt] = mean1; rstd1r[rt] = rstd1;
    float q1 = 0.f, q2 = 0.f;
#pragma unroll
    for (int n = 0; n < 2; ++n) {
      const int col = (nt0 + n) * 16 + quad * 4;
      floatx4 gg = *(const floatx4*)&g2[col];
      floatx4 bb = *(const floatx4*)&be2[col];
#pragma unroll
      for (int r = 0; r < 4; ++r) {
        float z = (acc2[n][rt][r] - mean1) * rstd1 * gg[r] + bb[r];
        q1 += z; q2 += z * z;
      }
    }
    q1 += __shfl_xor(q1, 16); q1 += __shfl_xor(q1, 32);
    q2 += __shfl_xor(q2, 16); q2 += __shfl_xor(q2, 32);
    if (quad == 0) { st[512 + tok * 4 + wave] = q1; st[768 + tok * 4 + wave] = q2; }
  }
  __syncthreads();

  // round 3: combine -> mean2/rstd2; final LN2+LN3 write
#pragma unroll
  for (int rt = 0; rt < 4; ++rt) {
    const int tok = rt * 16 + ln16;
    float s1 = 0.f, s2 = 0.f;
#pragma unroll
    for (int w4 = 0; w4 < 4; ++w4) { s1 += st[512 + tok * 4 + w4]; s2 += st[768 + tok * 4 + w4]; }
    const float mean2 = s1 * (1.0f / 128.0f);
    const float rstd2 = rsqrtf(s2 * (1.0f / 128.0f) - mean2 * mean2 + 1e-5f);
    const float mean1 = mean1r[rt], rstd1 = rstd1r[rt];
    float* orow = OUT + basef + (long)tok * 4096;
#pragma unroll
    for (int n = 0; n < 2; ++n) {
      const int col = (nt0 + n) * 16 + quad * 4;
      floatx4 gg2 = *(const floatx4*)&g2[col];
      floatx4 bb2 = *(const floatx4*)&be2[col];
      floatx4 gg3 = *(const floatx4*)&g3[col];
      floatx4 bb3 = *(const floatx4*)&be3[col];
      floatx4 o4;
#pragma unroll
      for (int r = 0; r < 4; ++r) {
        float z = (acc2[n][rt][r] - mean1) * rstd1 * gg2[r] + bb2[r];
        o4[r] = (z - mean2) * rstd2 * gg3[r] + bb3[r];
      }
      *(floatx4*)&orow[col] = o4;
    }
  }
}

// ---------------------------------------------------------------------------
extern "C" void kernel_launch(void* const* d_in, const int* in_sizes, int n_in,
                              void* d_out, int out_size, void* d_ws, size_t ws_size,
                              hipStream_t stream) {
  const float* x        = (const float*)d_in[0];
  const float* router   = (const float*)d_in[1];
  const float* w_router = (const float*)d_in[2];
  const float* b_router = (const float*)d_in[3];
  const float* w_k  = (const float*)d_in[4];
  const float* b_k  = (const float*)d_in[5];
  const float* w_v  = (const float*)d_in[6];
  const float* b_v  = (const float*)d_in[7];
  const float* w_q  = (const float*)d_in[8];
  const float* b_q  = (const float*)d_in[9];
  const float* m1w1 = (const float*)d_in[10];
  const float* m1b1 = (const float*)d_in[11];
  const float* m1w2 = (const float*)d_in[12];
  const float* m1b2 = (const float*)d_in[13];
  const float* m2w1 = (const float*)d_in[14];
  const float* m2b1 = (const float*)d_in[15];
  const float* m2w2 = (const float*)d_in[16];
  const float* m2b2 = (const float*)d_in[17];
  const float* g1  = (const float*)d_in[18];
  const float* be1 = (const float*)d_in[19];
  const float* g2  = (const float*)d_in[20];
  const float* be2 = (const float*)d_in[21];
  const float* g3  = (const float*)d_in[22];
  const float* be3 = (const float*)d_in[23];
  float* out = (float*)d_out;

  char* ws = (char*)d_ws;
  short* XPb = (short*)ws;                      // x_proj bf16: 32 MiB
  float* BUF = (float*)(ws + 33554432);         // 640 KiB
  short* w1p1 = (short*)(ws + 34209792);
  short* w2p1 = w1p1 + 65536;
  short* w1p2 = w2p1 + 65536;
  short* w2p2 = w1p2 + 65536;
  short* wqp  = w2p2 + 65536;
  short* wkp  = wqp + 16384;
  short* wvp  = wkp + 16384;
  short* wrp  = wvp + 16384;

  pack_all<<<1280, 256, 0, stream>>>(m1w1, m1w2, m2w1, m2w2, w_q, w_k, w_v, w_router,
                                     w1p1, w2p1, w1p2, w2p2, wqp, wkp, wvp, wrp);
  k_mlp_ln<<<2048, 256, 0, stream>>>(x, XPb, w1p1, m1b1, w2p1, m1b2, g1, be1);
  k_buffer<<<128, 256, 0, stream>>>(XPb, router, wkp, b_k, wvp, b_v, wrp, b_router, BUF);
  k_attn_mlp<<<2048, 256, 0, stream>>>(XPb, BUF, out, wqp, b_q,
                                       w1p2, m2b1, w2p2, m2b2,
                                       g2, be2, g3, be3);
}

// Round 10
// 318.881 us; speedup vs baseline: 1.0264x; 1.0264x over previous
//
#include <hip/hip_runtime.h>
#include <math.h>

// ---------------------------------------------------------------------------
// QuadraLayer fused, bf16-MFMA path, round 10.
// r9 (327us): attn r7-form 132us stable (r8 hoist regression confirmed real);
// mlp_ln hoisted kept (~11us real gain vs non-hoisted).
// r10 (attn-only changes):
//  1. residual snapshot: LN round-1 residual taken from xb (registers,
//     snapshotted before attn overwrites) instead of re-reading XPb global
//     (-32MB/dispatch).
//  2. attn2 uses all 256 threads: thread PAIR per (row,head); dot c-halves
//     combined via __shfl_xor(p,1); PV c-halves disjoint.
//  3. BUF->kv stage vectorized (float4).
// MFMA phases byte-identical to r9 (attn r7-form, mlp_ln r8-hoisted form).
// ---------------------------------------------------------------------------

typedef short short8 __attribute__((ext_vector_type(8)));
typedef short short4v __attribute__((ext_vector_type(4)));
typedef float floatx4 __attribute__((ext_vector_type(4)));

#define MFMA_BF16(a, b, c) __builtin_amdgcn_mfma_f32_16x16x32_bf16((a), (b), (c), 0, 0, 0)

__device__ __forceinline__ short f2b(float f) {
  unsigned u = __builtin_bit_cast(unsigned, f);
  u += 0x7FFFu + ((u >> 16) & 1u);
  return (short)(u >> 16);
}
__device__ __forceinline__ float b2f(short s) {
  unsigned u = ((unsigned)(unsigned short)s) << 16;
  return __builtin_bit_cast(float, u);
}
// gelu(v) = 0.5 v (1+erf(v/sqrt2)); erf via A&S 7.1.26 (|eps|<=1.5e-7)
__device__ __forceinline__ float gelu_fast(float v) {
  float z  = v * 0.70710678118654752f;
  float az = fabsf(z);
  float t  = __builtin_amdgcn_rcpf(1.0f + 0.3275911f * az);
  float poly = ((((1.061405429f * t - 1.453152027f) * t + 1.421413741f) * t
                 - 0.284496736f) * t + 0.254829592f) * t;
  float e = 1.0f - poly * __expf(-az * az);
  float erfv = copysignf(e, z);
  return 0.5f * v * (1.0f + erfv);
}

// ---------------------------------------------------------------------------
// Pack all weights into bf16 MFMA fragments.
// lane -> (free dim = lane&15, k = (lane>>4)*8+j); P[((nt*KS+ks)*64+lane)*8+j]
// ---------------------------------------------------------------------------
__global__ void pack_all(const float* __restrict__ m1w1, const float* __restrict__ m1w2,
                         const float* __restrict__ m2w1, const float* __restrict__ m2w2,
                         const float* __restrict__ wq,
                         const float* __restrict__ wk, const float* __restrict__ wv,
                         const float* __restrict__ wr,
                         short* __restrict__ w1p1, short* __restrict__ w2p1,
                         short* __restrict__ w1p2, short* __restrict__ w2p2,
                         short* __restrict__ wqp, short* __restrict__ wkp,
                         short* __restrict__ wvp, short* __restrict__ wrp) {
  int idx = blockIdx.x * 256 + threadIdx.x;
  const float* W; short* P; int KS, N, base;
  if (idx < 65536)       { W = m1w1; P = w1p1; KS = 4;  N = 512; base = 0; }
  else if (idx < 131072) { W = m1w2; P = w2p1; KS = 16; N = 128; base = 65536; }
  else if (idx < 196608) { W = m2w1; P = w1p2; KS = 4;  N = 512; base = 131072; }
  else if (idx < 262144) { W = m2w2; P = w2p2; KS = 16; N = 128; base = 196608; }
  else if (idx < 278528) { W = wq;   P = wqp;  KS = 4;  N = 128; base = 262144; }
  else if (idx < 294912) { W = wk;   P = wkp;  KS = 4;  N = 128; base = 278528; }
  else if (idx < 311296) { W = wv;   P = wvp;  KS = 4;  N = 128; base = 294912; }
  else if (idx < 327680) { W = wr;   P = wrp;  KS = 4;  N = 128; base = 311296; }
  else return;
  int i = idx - base;
  int j    = i & 7;
  int lane = (i >> 3) & 63;
  int ks   = (i >> 9) % KS;
  int nt   = i / (KS << 9);
  int k = ks * 32 + ((lane >> 4) << 3) + j;
  int n = nt * 16 + (lane & 15);
  P[i] = f2b(W[k * N + n]);
}

// ---------------------------------------------------------------------------
// Stage B: x_proj(bf16) = LN(x + MLP1(x)). 64 rows/block.
// Column-split GEMMs with hoisted B-fragment reads (r8 form).
// ---------------------------------------------------------------------------
__global__ __launch_bounds__(256, 4)
void k_mlp_ln(const float* __restrict__ X, short* __restrict__ OUTb,
              const short* __restrict__ w1p, const float* __restrict__ b1,
              const short* __restrict__ w2p, const float* __restrict__ b2,
              const float* __restrict__ g, const float* __restrict__ be) {
  __shared__ __align__(16) short xb[64 * 136];
  __shared__ __align__(16) short hb[64 * 136];
  __shared__ float2 st[256];              // [token][wave] partial (s1, s2)

  const int tid  = threadIdx.x;
  const int lane = tid & 63;
  const int wave = tid >> 6;
  const int quad = lane >> 4;
  const int ln16 = lane & 15;
  const long rowbase = (long)blockIdx.x * 64;
  const float* xsrc = X + rowbase * 128;

#pragma unroll
  for (int i = 0; i < 8; ++i) {
    int flat = tid + 256 * i;
    int r  = flat >> 5;
    int c4 = (flat & 31) << 2;
    floatx4 v = *(const floatx4*)(xsrc + r * 128 + c4);
    short4v s;
    s[0] = f2b(v[0]); s[1] = f2b(v[1]); s[2] = f2b(v[2]); s[3] = f2b(v[3]);
    *(short4v*)&xb[r * 136 + c4] = s;
  }
  __syncthreads();

  const int nt0 = wave * 2;          // this wave's GEMM2 output col tiles
  floatx4 acc2[2][4];                // [nt_local][row_tile]
#pragma unroll
  for (int n = 0; n < 2; ++n)
#pragma unroll
    for (int rt = 0; rt < 4; ++rt) acc2[n][rt] = (floatx4){0.f, 0.f, 0.f, 0.f};

#pragma unroll 1
  for (int qtr = 0; qtr < 4; ++qtr) {
    // ---- GEMM1 quarter: h col tiles ntg = qtr*8+nt0+{0,1}, all 64 rows ----
    const int ntgA = qtr * 8 + nt0;
    floatx4 a1[2][4];
#pragma unroll
    for (int n = 0; n < 2; ++n)
#pragma unroll
      for (int rt = 0; rt < 4; ++rt) a1[n][rt] = (floatx4){0.f, 0.f, 0.f, 0.f};
#pragma unroll
    for (int ks = 0; ks < 4; ++ks) {
      short8 bf[4];
#pragma unroll
      for (int rt = 0; rt < 4; ++rt)
        bf[rt] = *(const short8*)&xb[(rt * 16 + ln16) * 136 + ks * 32 + quad * 8];
      short8 af0 = *(const short8*)&w1p[((ntgA * 4 + ks) * 64 + lane) * 8];
      short8 af1 = *(const short8*)&w1p[(((ntgA + 1) * 4 + ks) * 64 + lane) * 8];
#pragma unroll
      for (int rt = 0; rt < 4; ++rt) a1[0][rt] = MFMA_BF16(af0, bf[rt], a1[0][rt]);
#pragma unroll
      for (int rt = 0; rt < 4; ++rt) a1[1][rt] = MFMA_BF16(af1, bf[rt], a1[1][rt]);
    }
#pragma unroll
    for (int n = 0; n < 2; ++n) {
      floatx4 bias = *(const floatx4*)&b1[(ntgA + n) * 16 + quad * 4];
#pragma unroll
      for (int rt = 0; rt < 4; ++rt) {
        short4v hv;
#pragma unroll
        for (int r = 0; r < 4; ++r) hv[r] = f2b(gelu_fast(a1[n][rt][r] + bias[r]));
        *(short4v*)&hb[(rt * 16 + ln16) * 136 + (nt0 + n) * 16 + quad * 4] = hv;
      }
    }
    __syncthreads();
    // ---- GEMM2 quarter: fixed output tiles nt0,nt0+1; K-slice qtr*4+ks ----
#pragma unroll
    for (int ks = 0; ks < 4; ++ks) {
      short8 bf[4];
#pragma unroll
      for (int rt = 0; rt < 4; ++rt)
        bf[rt] = *(const short8*)&hb[(rt * 16 + ln16) * 136 + ks * 32 + quad * 8];
      short8 af0 = *(const short8*)&w2p[((nt0 * 16 + qtr * 4 + ks) * 64 + lane) * 8];
      short8 af1 = *(const short8*)&w2p[(((nt0 + 1) * 16 + qtr * 4 + ks) * 64 + lane) * 8];
#pragma unroll
      for (int rt = 0; rt < 4; ++rt) acc2[0][rt] = MFMA_BF16(af0, bf[rt], acc2[0][rt]);
#pragma unroll
      for (int rt = 0; rt < 4; ++rt) acc2[1][rt] = MFMA_BF16(af1, bf[rt], acc2[1][rt]);
    }
    __syncthreads();
  }

  // residual + bias in-register; per-wave partial LN stats -> st[]
#pragma unroll
  for (int rt = 0; rt < 4; ++rt) {
    float p1 = 0.f, p2 = 0.f;
#pragma unroll
    for (int n = 0; n < 2; ++n) {
      const int col = (nt0 + n) * 16 + quad * 4;
      floatx4 bb = *(const floatx4*)&b2[col];
      floatx4 xres = *(const floatx4*)(xsrc + (rt * 16 + ln16) * 128 + col);
      floatx4 v;
#pragma unroll
      for (int r = 0; r < 4; ++r) {
        v[r] = acc2[n][rt][r] + bb[r] + xres[r];
        p1 += v[r]; p2 += v[r] * v[r];
      }
      acc2[n][rt] = v;
    }
    p1 += __shfl_xor(p1, 16); p1 += __shfl_xor(p1, 32);
    p2 += __shfl_xor(p2, 16); p2 += __shfl_xor(p2, 32);
    if (quad == 0) st[(rt * 16 + ln16) * 4 + wave] = (float2){p1, p2};
  }
  __syncthreads();

  // combine partials; each wave normalizes + writes its own 32 cols per row
#pragma unroll
  for (int rt = 0; rt < 4; ++rt) {
    const int tok = rt * 16 + ln16;
    float s1 = 0.f, s2 = 0.f;
#pragma unroll
    for (int w4 = 0; w4 < 4; ++w4) {
      float2 pp = st[tok * 4 + w4];
      s1 += pp.x; s2 += pp.y;
    }
    const float mean = s1 * (1.0f / 128.0f);
    const float rstd = rsqrtf(s2 * (1.0f / 128.0f) - mean * mean + 1e-5f);
    short* orow = OUTb + (rowbase + tok) * 128;
#pragma unroll
    for (int n = 0; n < 2; ++n) {
      const int col = (nt0 + n) * 16 + quad * 4;
      floatx4 gg = *(const floatx4*)&g[col];
      floatx4 bb = *(const floatx4*)&be[col];
      short4v o;
#pragma unroll
      for (int r = 0; r < 4; ++r)
        o[r] = f2b((acc2[n][rt][r] - mean) * rstd * gg[r] + bb[r]);
      *(short4v*)&orow[col] = o;
    }
  }
}

// ---------------------------------------------------------------------------
// Stage C: K/V (t<15) + router projections via MFMA, then banded attn1.
// One block per (b,l). LDS 23 KB. (unchanged, verified)
// ---------------------------------------------------------------------------
__global__ __launch_bounds__(256, 4)
void k_buffer(const short* __restrict__ XPb, const float* __restrict__ router,
              const short* __restrict__ wkp, const float* __restrict__ b_k,
              const short* __restrict__ wvp, const float* __restrict__ b_v,
              const short* __restrict__ wrp, const float* __restrict__ b_r,
              float* __restrict__ BUF) {
  __shared__ __align__(16) short ab[32 * 136];
  __shared__ __align__(16) short kp[16 * 136];
  __shared__ __align__(16) short vp[16 * 136];
  __shared__ __align__(16) short rp[16 * 136];
  __shared__ float sc[20 * 16];
  const int tid  = threadIdx.x;
  const int lane = tid & 63;
  const int wave = tid >> 6;
  const int quad = lane >> 4;
  const int ln16 = lane & 15;
  const int bl = blockIdx.x;
  const int b = bl >> 5, l = bl & 31;

  if (tid < 240) {
    int r = tid >> 4, c8 = (tid & 15) << 3;
    short8 v = *(const short8*)(XPb + (((long)b * 1024 + r) * 32 + l) * 128 + c8);
    *(short8*)&ab[r * 136 + c8] = v;
  }
  for (int i = tid; i < 320; i += 256) {
    int r = i >> 5, c4 = (i & 31) << 2;
    floatx4 v = *(const floatx4*)(router + (long)l * 1280 + r * 128 + c4);
    short4v s;
    s[0] = f2b(v[0]); s[1] = f2b(v[1]); s[2] = f2b(v[2]); s[3] = f2b(v[3]);
    *(short4v*)&ab[(16 + r) * 136 + c4] = s;
  }
  __syncthreads();

  for (int idx = wave; idx < 24; idx += 4) {
    const int m = idx >> 3, nt = idx & 7;
    const short* wp   = (m == 0) ? wkp : (m == 1) ? wvp : wrp;
    const float* bias = (m == 0) ? b_k : (m == 1) ? b_v : b_r;
    const int abase = (m == 2) ? 16 * 136 : 0;
    floatx4 acc = {0.f, 0.f, 0.f, 0.f};
#pragma unroll
    for (int ks = 0; ks < 4; ++ks) {
      short8 bf = *(const short8*)&ab[abase + ln16 * 136 + ks * 32 + quad * 8];
      short8 af = *(const short8*)&wp[((nt * 4 + ks) * 64 + lane) * 8];
      acc = MFMA_BF16(af, bf, acc);
    }
    floatx4 bb = *(const floatx4*)&bias[nt * 16 + quad * 4];
    short* dst = (m == 0) ? kp : (m == 1) ? vp : rp;
    short4v o;
#pragma unroll
    for (int r = 0; r < 4; ++r) o[r] = f2b(acc[r] + bb[r]);
    *(short4v*)&dst[ln16 * 136 + nt * 16 + quad * 4] = o;
  }
  __syncthreads();

  for (int t = tid; t < 220; t += 256) {
    int pair = t / 11, jrel = t - pair * 11;
    int i = pair >> 1, hd = pair & 1;
    int j = i - 5 + jrel;
    float s;
    if (j < 0) s = -1e30f;
    else {
      float a0 = 0.f, a1 = 0.f;
      for (int d = 0; d < 64; d += 2) {
        a0 += b2f(rp[i * 136 + hd * 64 + d])     * b2f(kp[j * 136 + hd * 64 + d]);
        a1 += b2f(rp[i * 136 + hd * 64 + d + 1]) * b2f(kp[j * 136 + hd * 64 + d + 1]);
      }
      s = fminf(fmaxf((a0 + a1) * 0.125f, -10000.0f), 10000.0f);
    }
    sc[pair * 16 + jrel] = s;
  }
  __syncthreads();
  if (tid < 20) {
    float mx = -1e30f;
    for (int jr = 0; jr < 11; ++jr) mx = fmaxf(mx, sc[tid * 16 + jr]);
    float den = 0.f, e[11];
    for (int jr = 0; jr < 11; ++jr) { e[jr] = __expf(sc[tid * 16 + jr] - mx); den += e[jr]; }
    float rden = 1.0f / den;
    for (int jr = 0; jr < 11; ++jr) sc[tid * 16 + jr] = e[jr] * rden;
  }
  __syncthreads();
  for (int e = tid; e < 1280; e += 256) {
    int pair = e >> 6, d = e & 63;
    int i = pair >> 1, hd = pair & 1;
    float o = 0.f;
#pragma unroll
    for (int jr = 0; jr < 11; ++jr) {
      int j = i - 5 + jr;
      int jc = (j < 0) ? 0 : j;
      o += sc[pair * 16 + jr] * b2f(vp[jc * 136 + hd * 64 + d]);
    }
    BUF[((bl * 2 + hd) * 10 + i) * 64 + d] = o;
  }
}

// ---------------------------------------------------------------------------
// Stage D: q-proj + attn2(10 keys) + MLP2 + LN2 + LN3 -> out.
// MFMA phases r7 form. Residual snapshot from xb; attn2 on 256 threads.
// ---------------------------------------------------------------------------
__global__ __launch_bounds__(256, 4)
void k_attn_mlp(const short* __restrict__ XPb, const float* __restrict__ BUF,
                float* __restrict__ OUT,
                const short* __restrict__ wqp, const float* __restrict__ bq,
                const short* __restrict__ w1p, const float* __restrict__ b1,
                const short* __restrict__ w2p, const float* __restrict__ b2,
                const float* __restrict__ g2, const float* __restrict__ be2,
                const float* __restrict__ g3, const float* __restrict__ be3) {
  __shared__ __align__(16) short xb[64 * 136];
  __shared__ __align__(16) short qh[64 * 136];
  __shared__ __align__(16) float kv[1280];   // K/V buffer; reused as LN partials

  const int tid  = threadIdx.x;
  const int lane = tid & 63;
  const int wave = tid >> 6;
  const int quad = lane >> 4;
  const int ln16 = lane & 15;

  const int bx = blockIdx.x;
  const int bl = bx >> 4;
  const int tt = bx & 15;
  const int b = bl >> 5, l = bl & 31;
  const int t0 = tt * 64;
  const long basef = ((long)(b * 1024 + t0) * 32 + l) * 128;

#pragma unroll
  for (int i = 0; i < 4; ++i) {
    int flat = tid + 256 * i;
    int r  = flat >> 4;
    int c8 = (flat & 15) << 3;
    short8 v = *(const short8*)(XPb + basef + (long)r * 4096 + c8);
    *(short8*)&xb[r * 136 + c8] = v;
  }
  {
    const floatx4* src = (const floatx4*)(BUF + (long)bl * 1280);
    for (int i = tid; i < 320; i += 256) ((floatx4*)kv)[i] = src[i];
  }
  __syncthreads();

  const int nt0 = wave * 2;

  // residual snapshot: this thread's LN slice of x_proj, before attn
  // overwrites xb. res[rt][n] = xb[rt*16+ln16][ (nt0+n)*16 + quad*4 .. +3 ]
  short4v res[4][2];
#pragma unroll
  for (int rt = 0; rt < 4; ++rt)
#pragma unroll
    for (int n = 0; n < 2; ++n)
      res[rt][n] = *(const short4v*)&xb[(rt * 16 + ln16) * 136 + (nt0 + n) * 16 + quad * 4];

  // q-proj, column-split (r7 form): wave owns col tiles {2w, 2w+1}
#pragma unroll
  for (int n = 0; n < 2; ++n) {
    const int nt = nt0 + n;
    short8 af[4];
#pragma unroll
    for (int ks = 0; ks < 4; ++ks)
      af[ks] = *(const short8*)&wqp[((nt * 4 + ks) * 64 + lane) * 8];
    floatx4 a1[4];
#pragma unroll
    for (int rt = 0; rt < 4; ++rt) a1[rt] = (floatx4){0.f, 0.f, 0.f, 0.f};
#pragma unroll
    for (int ks = 0; ks < 4; ++ks)
#pragma unroll
      for (int rt = 0; rt < 4; ++rt) {
        short8 bf = *(const short8*)&xb[(rt * 16 + ln16) * 136 + ks * 32 + quad * 8];
        a1[rt] = MFMA_BF16(af[ks], bf, a1[rt]);
      }
    floatx4 bb = *(const floatx4*)&bq[nt * 16 + quad * 4];
#pragma unroll
    for (int rt = 0; rt < 4; ++rt) {
      short4v qv;
#pragma unroll
      for (int r = 0; r < 4; ++r) qv[r] = f2b(a1[rt][r] + bb[r]);
      *(short4v*)&qh[(rt * 16 + ln16) * 136 + nt * 16 + quad * 4] = qv;
    }
  }
  __syncthreads();

  // attn2: 256 threads; thread pair per (row, head). half = c-split.
  {
    const int row  = tid >> 2;
    const int hd   = (tid >> 1) & 1;
    const int half = tid & 1;
    const int t = t0 + row;
    const short* qrow = &qh[row * 136 + hd * 64];
    const float* kvh  = &kv[hd * 640];
    float p[10];
#pragma unroll
    for (int j = 0; j < 10; ++j) p[j] = 0.f;
#pragma unroll
    for (int ci = 0; ci < 4; ++ci) {
      const int c = half * 4 + ci;
      short8 qs = *(const short8*)&qrow[c * 8];
      float qf[8];
#pragma unroll
      for (int u = 0; u < 8; ++u) qf[u] = b2f(qs[u]);
#pragma unroll
      for (int j = 0; j < 10; ++j) {
        const float* kp = &kvh[j * 64 + c * 8];
        floatx4 k0 = *(const floatx4*)kp;
        floatx4 k1 = *(const floatx4*)(kp + 4);
        p[j] += qf[0] * k0[0] + qf[1] * k0[1] + qf[2] * k0[2] + qf[3] * k0[3]
              + qf[4] * k1[0] + qf[5] * k1[1] + qf[6] * k1[2] + qf[7] * k1[3];
      }
    }
#pragma unroll
    for (int j = 0; j < 10; ++j) p[j] += __shfl_xor(p[j], 1);
    const bool full = (t >= 10);
    const int jlo = t - 5, jhi = t + 5;
    float mx = -1e30f;
#pragma unroll
    for (int j = 0; j < 10; ++j) {
      float s = fminf(fmaxf(p[j] * 0.125f, -10000.0f), 10000.0f);
      s = (full || (j >= jlo && j <= jhi)) ? s : -1e30f;
      p[j] = s; mx = fmaxf(mx, s);
    }
    float den = 0.f;
#pragma unroll
    for (int j = 0; j < 10; ++j) { p[j] = __expf(p[j] - mx); den += p[j]; }
    const float rden = 1.0f / den;
#pragma unroll
    for (int j = 0; j < 10; ++j) p[j] *= rden;
#pragma unroll
    for (int ci = 0; ci < 8; ++ci) {
      const int c = half * 8 + ci;
      floatx4 o = {0.f, 0.f, 0.f, 0.f};
#pragma unroll
      for (int j = 0; j < 10; ++j) {
        floatx4 vv = *(const floatx4*)&kvh[j * 64 + c * 4];
        o += p[j] * vv;
      }
      short4v s;
#pragma unroll
      for (int r = 0; r < 4; ++r) s[r] = f2b(o[r]);
      *(short4v*)&xb[row * 136 + hd * 64 + c * 4] = s;
    }
  }
  __syncthreads();

  // MLP2, column-split (r7 form: af[4] per n, bf read per rt)
  floatx4 acc2[2][4];
#pragma unroll
  for (int n = 0; n < 2; ++n)
#pragma unroll
    for (int rt = 0; rt < 4; ++rt) acc2[n][rt] = (floatx4){0.f, 0.f, 0.f, 0.f};

#pragma unroll 1
  for (int qtr = 0; qtr < 4; ++qtr) {
#pragma unroll
    for (int n = 0; n < 2; ++n) {
      const int ntg = qtr * 8 + nt0 + n;
      short8 af[4];
#pragma unroll
      for (int ks = 0; ks < 4; ++ks)
        af[ks] = *(const short8*)&w1p[((ntg * 4 + ks) * 64 + lane) * 8];
      floatx4 a1[4];
#pragma unroll
      for (int rt = 0; rt < 4; ++rt) a1[rt] = (floatx4){0.f, 0.f, 0.f, 0.f};
#pragma unroll
      for (int ks = 0; ks < 4; ++ks)
#pragma unroll
        for (int rt = 0; rt < 4; ++rt) {
          short8 bf = *(const short8*)&xb[(rt * 16 + ln16) * 136 + ks * 32 + quad * 8];
          a1[rt] = MFMA_BF16(af[ks], bf, a1[rt]);
        }
      floatx4 bias = *(const floatx4*)&b1[ntg * 16 + quad * 4];
#pragma unroll
      for (int rt = 0; rt < 4; ++rt) {
        short4v hv;
#pragma unroll
        for (int r = 0; r < 4; ++r) hv[r] = f2b(gelu_fast(a1[rt][r] + bias[r]));
        *(short4v*)&qh[(rt * 16 + ln16) * 136 + (nt0 + n) * 16 + quad * 4] = hv;
      }
    }
    __syncthreads();
#pragma unroll
    for (int n = 0; n < 2; ++n) {
      const int nt = nt0 + n;
      short8 af[4];
#pragma unroll
      for (int ks = 0; ks < 4; ++ks)
        af[ks] = *(const short8*)&w2p[((nt * 16 + qtr * 4 + ks) * 64 + lane) * 8];
#pragma unroll
      for (int ks = 0; ks < 4; ++ks)
#pragma unroll
        for (int rt = 0; rt < 4; ++rt) {
          short8 bf = *(const short8*)&qh[(rt * 16 + ln16) * 136 + ks * 32 + quad * 8];
          acc2[n][rt] = MFMA_BF16(af[ks], bf, acc2[n][rt]);
        }
    }
    __syncthreads();
  }

  // ---- dual-LN epilogue via kv[] reuse (kv dead after attn phase) ----
  float* st = kv;          // st[0..255]=s1, st[256..511]=s2, [512..767]=z1, [768..1023]=z2
  float mean1r[4], rstd1r[4];

  // round 1: v = acc2 + b2 + residual(snapshot); per-wave partials
#pragma unroll
  for (int rt = 0; rt < 4; ++rt) {
    const int tok = rt * 16 + ln16;
    float p1 = 0.f, p2 = 0.f;
#pragma unroll
    for (int n = 0; n < 2; ++n) {
      const int col = (nt0 + n) * 16 + quad * 4;
      floatx4 bb = *(const floatx4*)&b2[col];
      short4v xs4 = res[rt][n];
      floatx4 v;
#pragma unroll
      for (int r = 0; r < 4; ++r) {
        v[r] = acc2[n][rt][r] + bb[r] + b2f(xs4[r]);
        p1 += v[r]; p2 += v[r] * v[r];
      }
      acc2[n][rt] = v;
    }
    p1 += __shfl_xor(p1, 16); p1 += __shfl_xor(p1, 32);
    p2 += __shfl_xor(p2, 16); p2 += __shfl_xor(p2, 32);
    if (quad == 0) { st[tok * 4 + wave] = p1; st[256 + tok * 4 + wave] = p2; }
  }
  __syncthreads();

  // round 2: combine -> mean1/rstd1; z-partials -> st[512..]
#pragma unroll
  for (int rt = 0; rt < 4; ++rt) {
    const int tok = rt * 16 + ln16;
    float s1 = 0.f, s2 = 0.f;
#pragma unroll
    for (int w4 = 0; w4 < 4; ++w4) { s1 += st[tok * 4 + w4]; s2 += st[256 + tok * 4 + w4]; }
    const float mean1 = s1 * (1.0f / 128.0f);
    const float rstd1 = rsqrtf(s2 * (1.0f / 128.0f) - mean1 * mean1 + 1e-5f);
    mean1r[rt] = mean1; rstd1r[rt] = rstd1;
    float q1 = 0.f, q2 = 0.f;
#pragma unroll
    for (int n = 0; n < 2; ++n) {
      const int col = (nt0 + n) * 16 + quad * 4;
      floatx4 gg = *(const floatx4*)&g2[col];
      floatx4 bb = *(const floatx4*)&be2[col];
#pragma unroll
      for (int r = 0; r < 4; ++r) {
        float z = (acc2[n][rt][r] - mean1) * rstd1 * gg[r] + bb[r];
        q1 += z; q2 += z * z;
      }
    }
    q1 += __shfl_xor(q1, 16); q1 += __shfl_xor(q1, 32);
    q2 += __shfl_xor(q2, 16); q2 += __shfl_xor(q2, 32);
    if (quad == 0) { st[512 + tok * 4 + wave] = q1; st[768 + tok * 4 + wave] = q2; }
  }
  __syncthreads();

  // round 3: combine -> mean2/rstd2; final LN2+LN3 write
#pragma unroll
  for (int rt = 0; rt < 4; ++rt) {
    const int tok = rt * 16 + ln16;
    float s1 = 0.f, s2 = 0.f;
#pragma unroll
    for (int w4 = 0; w4 < 4; ++w4) { s1 += st[512 + tok * 4 + w4]; s2 += st[768 + tok * 4 + w4]; }
    const float mean2 = s1 * (1.0f / 128.0f);
    const float rstd2 = rsqrtf(s2 * (1.0f / 128.0f) - mean2 * mean2 + 1e-5f);
    const float mean1 = mean1r[rt], rstd1 = rstd1r[rt];
    float* orow = OUT + basef + (long)tok * 4096;
#pragma unroll
    for (int n = 0; n < 2; ++n) {
      const int col = (nt0 + n) * 16 + quad * 4;
      floatx4 gg2 = *(const floatx4*)&g2[col];
      floatx4 bb2 = *(const floatx4*)&be2[col];
      floatx4 gg3 = *(const floatx4*)&g3[col];
      floatx4 bb3 = *(const floatx4*)&be3[col];
      floatx4 o4;
#pragma unroll
      for (int r = 0; r < 4; ++r) {
        float z = (acc2[n][rt][r] - mean1) * rstd1 * gg2[r] + bb2[r];
        o4[r] = (z - mean2) * rstd2 * gg3[r] + bb3[r];
      }
      *(floatx4*)&orow[col] = o4;
    }
  }
}

// ---------------------------------------------------------------------------
extern "C" void kernel_launch(void* const* d_in, const int* in_sizes, int n_in,
                              void* d_out, int out_size, void* d_ws, size_t ws_size,
                              hipStream_t stream) {
  const float* x        = (const float*)d_in[0];
  const float* router   = (const float*)d_in[1];
  const float* w_router = (const float*)d_in[2];
  const float* b_router = (const float*)d_in[3];
  const float* w_k  = (const float*)d_in[4];
  const float* b_k  = (const float*)d_in[5];
  const float* w_v  = (const float*)d_in[6];
  const float* b_v  = (const float*)d_in[7];
  const float* w_q  = (const float*)d_in[8];
  const float* b_q  = (const float*)d_in[9];
  const float* m1w1 = (const float*)d_in[10];
  const float* m1b1 = (const float*)d_in[11];
  const float* m1w2 = (const float*)d_in[12];
  const float* m1b2 = (const float*)d_in[13];
  const float* m2w1 = (const float*)d_in[14];
  const float* m2b1 = (const float*)d_in[15];
  const float* m2w2 = (const float*)d_in[16];
  const float* m2b2 = (const float*)d_in[17];
  const float* g1  = (const float*)d_in[18];
  const float* be1 = (const float*)d_in[19];
  const float* g2  = (const float*)d_in[20];
  const float* be2 = (const float*)d_in[21];
  const float* g3  = (const float*)d_in[22];
  const float* be3 = (const float*)d_in[23];
  float* out = (float*)d_out;

  char* ws = (char*)d_ws;
  short* XPb = (short*)ws;                      // x_proj bf16: 32 MiB
  float* BUF = (float*)(ws + 33554432);         // 640 KiB
  short* w1p1 = (short*)(ws + 34209792);
  short* w2p1 = w1p1 + 65536;
  short* w1p2 = w2p1 + 65536;
  short* w2p2 = w1p2 + 65536;
  short* wqp  = w2p2 + 65536;
  short* wkp  = wqp + 16384;
  short* wvp  = wkp + 16384;
  short* wrp  = wvp + 16384;

  pack_all<<<1280, 256, 0, stream>>>(m1w1, m1w2, m2w1, m2w2, w_q, w_k, w_v, w_router,
                                     w1p1, w2p1, w1p2, w2p2, wqp, wkp, wvp, wrp);
  k_mlp_ln<<<2048, 256, 0, stream>>>(x, XPb, w1p1, m1b1, w2p1, m1b2, g1, be1);
  k_buffer<<<128, 256, 0, stream>>>(XPb, router, wkp, b_k, wvp, b_v, wrp, b_router, BUF);
  k_attn_mlp<<<2048, 256, 0, stream>>>(XPb, BUF, out, wqp, b_q,
                                       w1p2, m2b1, w2p2, m2b2,
                                       g2, be2, g3, be3);
}

// Round 11
// 312.948 us; speedup vs baseline: 1.0458x; 1.0190x over previous
//
#include <hip/hip_runtime.h>
#include <math.h>

// ---------------------------------------------------------------------------
// QuadraLayer fused, bf16-MFMA path, round 11.
// r10 (318.9us): attn 121.4us — 256-thread attn2 + float4 BUF staging won,
// BUT res[][] register snapshot spilled to scratch (WRITE_SIZE 97->143MB,
// FETCH 50->61MB = ~67MB scratch round-trip).
// r11: (1) attn LN residual back to XPb global read (L2-resident; no spill).
//      (2) mlp_ln LN residual from xb LDS (xb never overwritten there —
//          read at use-time, no snapshot) replacing 64MB fp32 re-read.
// MFMA phases unchanged (attn r7-form, mlp_ln r8-hoisted form).
// ---------------------------------------------------------------------------

typedef short short8 __attribute__((ext_vector_type(8)));
typedef short short4v __attribute__((ext_vector_type(4)));
typedef float floatx4 __attribute__((ext_vector_type(4)));

#define MFMA_BF16(a, b, c) __builtin_amdgcn_mfma_f32_16x16x32_bf16((a), (b), (c), 0, 0, 0)

__device__ __forceinline__ short f2b(float f) {
  unsigned u = __builtin_bit_cast(unsigned, f);
  u += 0x7FFFu + ((u >> 16) & 1u);
  return (short)(u >> 16);
}
__device__ __forceinline__ float b2f(short s) {
  unsigned u = ((unsigned)(unsigned short)s) << 16;
  return __builtin_bit_cast(float, u);
}
// gelu(v) = 0.5 v (1+erf(v/sqrt2)); erf via A&S 7.1.26 (|eps|<=1.5e-7)
__device__ __forceinline__ float gelu_fast(float v) {
  float z  = v * 0.70710678118654752f;
  float az = fabsf(z);
  float t  = __builtin_amdgcn_rcpf(1.0f + 0.3275911f * az);
  float poly = ((((1.061405429f * t - 1.453152027f) * t + 1.421413741f) * t
                 - 0.284496736f) * t + 0.254829592f) * t;
  float e = 1.0f - poly * __expf(-az * az);
  float erfv = copysignf(e, z);
  return 0.5f * v * (1.0f + erfv);
}

// ---------------------------------------------------------------------------
// Pack all weights into bf16 MFMA fragments.
// lane -> (free dim = lane&15, k = (lane>>4)*8+j); P[((nt*KS+ks)*64+lane)*8+j]
// ---------------------------------------------------------------------------
__global__ void pack_all(const float* __restrict__ m1w1, const float* __restrict__ m1w2,
                         const float* __restrict__ m2w1, const float* __restrict__ m2w2,
                         const float* __restrict__ wq,
                         const float* __restrict__ wk, const float* __restrict__ wv,
                         const float* __restrict__ wr,
                         short* __restrict__ w1p1, short* __restrict__ w2p1,
                         short* __restrict__ w1p2, short* __restrict__ w2p2,
                         short* __restrict__ wqp, short* __restrict__ wkp,
                         short* __restrict__ wvp, short* __restrict__ wrp) {
  int idx = blockIdx.x * 256 + threadIdx.x;
  const float* W; short* P; int KS, N, base;
  if (idx < 65536)       { W = m1w1; P = w1p1; KS = 4;  N = 512; base = 0; }
  else if (idx < 131072) { W = m1w2; P = w2p1; KS = 16; N = 128; base = 65536; }
  else if (idx < 196608) { W = m2w1; P = w1p2; KS = 4;  N = 512; base = 131072; }
  else if (idx < 262144) { W = m2w2; P = w2p2; KS = 16; N = 128; base = 196608; }
  else if (idx < 278528) { W = wq;   P = wqp;  KS = 4;  N = 128; base = 262144; }
  else if (idx < 294912) { W = wk;   P = wkp;  KS = 4;  N = 128; base = 278528; }
  else if (idx < 311296) { W = wv;   P = wvp;  KS = 4;  N = 128; base = 294912; }
  else if (idx < 327680) { W = wr;   P = wrp;  KS = 4;  N = 128; base = 311296; }
  else return;
  int i = idx - base;
  int j    = i & 7;
  int lane = (i >> 3) & 63;
  int ks   = (i >> 9) % KS;
  int nt   = i / (KS << 9);
  int k = ks * 32 + ((lane >> 4) << 3) + j;
  int n = nt * 16 + (lane & 15);
  P[i] = f2b(W[k * N + n]);
}

// ---------------------------------------------------------------------------
// Stage B: x_proj(bf16) = LN(x + MLP1(x)). 64 rows/block.
// Column-split GEMMs with hoisted B-fragment reads (r8 form).
// LN residual from xb LDS (bf16) — xb is never overwritten in this kernel.
// ---------------------------------------------------------------------------
__global__ __launch_bounds__(256, 4)
void k_mlp_ln(const float* __restrict__ X, short* __restrict__ OUTb,
              const short* __restrict__ w1p, const float* __restrict__ b1,
              const short* __restrict__ w2p, const float* __restrict__ b2,
              const float* __restrict__ g, const float* __restrict__ be) {
  __shared__ __align__(16) short xb[64 * 136];
  __shared__ __align__(16) short hb[64 * 136];
  __shared__ float2 st[256];              // [token][wave] partial (s1, s2)

  const int tid  = threadIdx.x;
  const int lane = tid & 63;
  const int wave = tid >> 6;
  const int quad = lane >> 4;
  const int ln16 = lane & 15;
  const long rowbase = (long)blockIdx.x * 64;
  const float* xsrc = X + rowbase * 128;

#pragma unroll
  for (int i = 0; i < 8; ++i) {
    int flat = tid + 256 * i;
    int r  = flat >> 5;
    int c4 = (flat & 31) << 2;
    floatx4 v = *(const floatx4*)(xsrc + r * 128 + c4);
    short4v s;
    s[0] = f2b(v[0]); s[1] = f2b(v[1]); s[2] = f2b(v[2]); s[3] = f2b(v[3]);
    *(short4v*)&xb[r * 136 + c4] = s;
  }
  __syncthreads();

  const int nt0 = wave * 2;          // this wave's GEMM2 output col tiles
  floatx4 acc2[2][4];                // [nt_local][row_tile]
#pragma unroll
  for (int n = 0; n < 2; ++n)
#pragma unroll
    for (int rt = 0; rt < 4; ++rt) acc2[n][rt] = (floatx4){0.f, 0.f, 0.f, 0.f};

#pragma unroll 1
  for (int qtr = 0; qtr < 4; ++qtr) {
    // ---- GEMM1 quarter: h col tiles ntg = qtr*8+nt0+{0,1}, all 64 rows ----
    const int ntgA = qtr * 8 + nt0;
    floatx4 a1[2][4];
#pragma unroll
    for (int n = 0; n < 2; ++n)
#pragma unroll
      for (int rt = 0; rt < 4; ++rt) a1[n][rt] = (floatx4){0.f, 0.f, 0.f, 0.f};
#pragma unroll
    for (int ks = 0; ks < 4; ++ks) {
      short8 bf[4];
#pragma unroll
      for (int rt = 0; rt < 4; ++rt)
        bf[rt] = *(const short8*)&xb[(rt * 16 + ln16) * 136 + ks * 32 + quad * 8];
      short8 af0 = *(const short8*)&w1p[((ntgA * 4 + ks) * 64 + lane) * 8];
      short8 af1 = *(const short8*)&w1p[(((ntgA + 1) * 4 + ks) * 64 + lane) * 8];
#pragma unroll
      for (int rt = 0; rt < 4; ++rt) a1[0][rt] = MFMA_BF16(af0, bf[rt], a1[0][rt]);
#pragma unroll
      for (int rt = 0; rt < 4; ++rt) a1[1][rt] = MFMA_BF16(af1, bf[rt], a1[1][rt]);
    }
#pragma unroll
    for (int n = 0; n < 2; ++n) {
      floatx4 bias = *(const floatx4*)&b1[(ntgA + n) * 16 + quad * 4];
#pragma unroll
      for (int rt = 0; rt < 4; ++rt) {
        short4v hv;
#pragma unroll
        for (int r = 0; r < 4; ++r) hv[r] = f2b(gelu_fast(a1[n][rt][r] + bias[r]));
        *(short4v*)&hb[(rt * 16 + ln16) * 136 + (nt0 + n) * 16 + quad * 4] = hv;
      }
    }
    __syncthreads();
    // ---- GEMM2 quarter: fixed output tiles nt0,nt0+1; K-slice qtr*4+ks ----
#pragma unroll
    for (int ks = 0; ks < 4; ++ks) {
      short8 bf[4];
#pragma unroll
      for (int rt = 0; rt < 4; ++rt)
        bf[rt] = *(const short8*)&hb[(rt * 16 + ln16) * 136 + ks * 32 + quad * 8];
      short8 af0 = *(const short8*)&w2p[((nt0 * 16 + qtr * 4 + ks) * 64 + lane) * 8];
      short8 af1 = *(const short8*)&w2p[(((nt0 + 1) * 16 + qtr * 4 + ks) * 64 + lane) * 8];
#pragma unroll
      for (int rt = 0; rt < 4; ++rt) acc2[0][rt] = MFMA_BF16(af0, bf[rt], acc2[0][rt]);
#pragma unroll
      for (int rt = 0; rt < 4; ++rt) acc2[1][rt] = MFMA_BF16(af1, bf[rt], acc2[1][rt]);
    }
    __syncthreads();
  }

  // residual (from xb LDS, bf16) + bias; per-wave partial LN stats -> st[]
#pragma unroll
  for (int rt = 0; rt < 4; ++rt) {
    float p1 = 0.f, p2 = 0.f;
#pragma unroll
    for (int n = 0; n < 2; ++n) {
      const int col = (nt0 + n) * 16 + quad * 4;
      floatx4 bb = *(const floatx4*)&b2[col];
      short4v xs4 = *(const short4v*)&xb[(rt * 16 + ln16) * 136 + col];
      floatx4 v;
#pragma unroll
      for (int r = 0; r < 4; ++r) {
        v[r] = acc2[n][rt][r] + bb[r] + b2f(xs4[r]);
        p1 += v[r]; p2 += v[r] * v[r];
      }
      acc2[n][rt] = v;
    }
    p1 += __shfl_xor(p1, 16); p1 += __shfl_xor(p1, 32);
    p2 += __shfl_xor(p2, 16); p2 += __shfl_xor(p2, 32);
    if (quad == 0) st[(rt * 16 + ln16) * 4 + wave] = (float2){p1, p2};
  }
  __syncthreads();

  // combine partials; each wave normalizes + writes its own 32 cols per row
#pragma unroll
  for (int rt = 0; rt < 4; ++rt) {
    const int tok = rt * 16 + ln16;
    float s1 = 0.f, s2 = 0.f;
#pragma unroll
    for (int w4 = 0; w4 < 4; ++w4) {
      float2 pp = st[tok * 4 + w4];
      s1 += pp.x; s2 += pp.y;
    }
    const float mean = s1 * (1.0f / 128.0f);
    const float rstd = rsqrtf(s2 * (1.0f / 128.0f) - mean * mean + 1e-5f);
    short* orow = OUTb + (rowbase + tok) * 128;
#pragma unroll
    for (int n = 0; n < 2; ++n) {
      const int col = (nt0 + n) * 16 + quad * 4;
      floatx4 gg = *(const floatx4*)&g[col];
      floatx4 bb = *(const floatx4*)&be[col];
      short4v o;
#pragma unroll
      for (int r = 0; r < 4; ++r)
        o[r] = f2b((acc2[n][rt][r] - mean) * rstd * gg[r] + bb[r]);
      *(short4v*)&orow[col] = o;
    }
  }
}

// ---------------------------------------------------------------------------
// Stage C: K/V (t<15) + router projections via MFMA, then banded attn1.
// One block per (b,l). LDS 23 KB. (unchanged, verified)
// ---------------------------------------------------------------------------
__global__ __launch_bounds__(256, 4)
void k_buffer(const short* __restrict__ XPb, const float* __restrict__ router,
              const short* __restrict__ wkp, const float* __restrict__ b_k,
              const short* __restrict__ wvp, const float* __restrict__ b_v,
              const short* __restrict__ wrp, const float* __restrict__ b_r,
              float* __restrict__ BUF) {
  __shared__ __align__(16) short ab[32 * 136];
  __shared__ __align__(16) short kp[16 * 136];
  __shared__ __align__(16) short vp[16 * 136];
  __shared__ __align__(16) short rp[16 * 136];
  __shared__ float sc[20 * 16];
  const int tid  = threadIdx.x;
  const int lane = tid & 63;
  const int wave = tid >> 6;
  const int quad = lane >> 4;
  const int ln16 = lane & 15;
  const int bl = blockIdx.x;
  const int b = bl >> 5, l = bl & 31;

  if (tid < 240) {
    int r = tid >> 4, c8 = (tid & 15) << 3;
    short8 v = *(const short8*)(XPb + (((long)b * 1024 + r) * 32 + l) * 128 + c8);
    *(short8*)&ab[r * 136 + c8] = v;
  }
  for (int i = tid; i < 320; i += 256) {
    int r = i >> 5, c4 = (i & 31) << 2;
    floatx4 v = *(const floatx4*)(router + (long)l * 1280 + r * 128 + c4);
    short4v s;
    s[0] = f2b(v[0]); s[1] = f2b(v[1]); s[2] = f2b(v[2]); s[3] = f2b(v[3]);
    *(short4v*)&ab[(16 + r) * 136 + c4] = s;
  }
  __syncthreads();

  for (int idx = wave; idx < 24; idx += 4) {
    const int m = idx >> 3, nt = idx & 7;
    const short* wp   = (m == 0) ? wkp : (m == 1) ? wvp : wrp;
    const float* bias = (m == 0) ? b_k : (m == 1) ? b_v : b_r;
    const int abase = (m == 2) ? 16 * 136 : 0;
    floatx4 acc = {0.f, 0.f, 0.f, 0.f};
#pragma unroll
    for (int ks = 0; ks < 4; ++ks) {
      short8 bf = *(const short8*)&ab[abase + ln16 * 136 + ks * 32 + quad * 8];
      short8 af = *(const short8*)&wp[((nt * 4 + ks) * 64 + lane) * 8];
      acc = MFMA_BF16(af, bf, acc);
    }
    floatx4 bb = *(const floatx4*)&bias[nt * 16 + quad * 4];
    short* dst = (m == 0) ? kp : (m == 1) ? vp : rp;
    short4v o;
#pragma unroll
    for (int r = 0; r < 4; ++r) o[r] = f2b(acc[r] + bb[r]);
    *(short4v*)&dst[ln16 * 136 + nt * 16 + quad * 4] = o;
  }
  __syncthreads();

  for (int t = tid; t < 220; t += 256) {
    int pair = t / 11, jrel = t - pair * 11;
    int i = pair >> 1, hd = pair & 1;
    int j = i - 5 + jrel;
    float s;
    if (j < 0) s = -1e30f;
    else {
      float a0 = 0.f, a1 = 0.f;
      for (int d = 0; d < 64; d += 2) {
        a0 += b2f(rp[i * 136 + hd * 64 + d])     * b2f(kp[j * 136 + hd * 64 + d]);
        a1 += b2f(rp[i * 136 + hd * 64 + d + 1]) * b2f(kp[j * 136 + hd * 64 + d + 1]);
      }
      s = fminf(fmaxf((a0 + a1) * 0.125f, -10000.0f), 10000.0f);
    }
    sc[pair * 16 + jrel] = s;
  }
  __syncthreads();
  if (tid < 20) {
    float mx = -1e30f;
    for (int jr = 0; jr < 11; ++jr) mx = fmaxf(mx, sc[tid * 16 + jr]);
    float den = 0.f, e[11];
    for (int jr = 0; jr < 11; ++jr) { e[jr] = __expf(sc[tid * 16 + jr] - mx); den += e[jr]; }
    float rden = 1.0f / den;
    for (int jr = 0; jr < 11; ++jr) sc[tid * 16 + jr] = e[jr] * rden;
  }
  __syncthreads();
  for (int e = tid; e < 1280; e += 256) {
    int pair = e >> 6, d = e & 63;
    int i = pair >> 1, hd = pair & 1;
    float o = 0.f;
#pragma unroll
    for (int jr = 0; jr < 11; ++jr) {
      int j = i - 5 + jr;
      int jc = (j < 0) ? 0 : j;
      o += sc[pair * 16 + jr] * b2f(vp[jc * 136 + hd * 64 + d]);
    }
    BUF[((bl * 2 + hd) * 10 + i) * 64 + d] = o;
  }
}

// ---------------------------------------------------------------------------
// Stage D: q-proj + attn2(10 keys) + MLP2 + LN2 + LN3 -> out.
// MFMA phases r7 form. attn2 on 256 threads; LN residual from XPb (L2).
// ---------------------------------------------------------------------------
__global__ __launch_bounds__(256, 4)
void k_attn_mlp(const short* __restrict__ XPb, const float* __restrict__ BUF,
                float* __restrict__ OUT,
                const short* __restrict__ wqp, const float* __restrict__ bq,
                const short* __restrict__ w1p, const float* __restrict__ b1,
                const short* __restrict__ w2p, const float* __restrict__ b2,
                const float* __restrict__ g2, const float* __restrict__ be2,
                const float* __restrict__ g3, const float* __restrict__ be3) {
  __shared__ __align__(16) short xb[64 * 136];
  __shared__ __align__(16) short qh[64 * 136];
  __shared__ __align__(16) float kv[1280];   // K/V buffer; reused as LN partials

  const int tid  = threadIdx.x;
  const int lane = tid & 63;
  const int wave = tid >> 6;
  const int quad = lane >> 4;
  const int ln16 = lane & 15;

  const int bx = blockIdx.x;
  const int bl = bx >> 4;
  const int tt = bx & 15;
  const int b = bl >> 5, l = bl & 31;
  const int t0 = tt * 64;
  const long basef = ((long)(b * 1024 + t0) * 32 + l) * 128;

#pragma unroll
  for (int i = 0; i < 4; ++i) {
    int flat = tid + 256 * i;
    int r  = flat >> 4;
    int c8 = (flat & 15) << 3;
    short8 v = *(const short8*)(XPb + basef + (long)r * 4096 + c8);
    *(short8*)&xb[r * 136 + c8] = v;
  }
  {
    const floatx4* src = (const floatx4*)(BUF + (long)bl * 1280);
    for (int i = tid; i < 320; i += 256) ((floatx4*)kv)[i] = src[i];
  }
  __syncthreads();

  const int nt0 = wave * 2;

  // q-proj, column-split (r7 form): wave owns col tiles {2w, 2w+1}
#pragma unroll
  for (int n = 0; n < 2; ++n) {
    const int nt = nt0 + n;
    short8 af[4];
#pragma unroll
    for (int ks = 0; ks < 4; ++ks)
      af[ks] = *(const short8*)&wqp[((nt * 4 + ks) * 64 + lane) * 8];
    floatx4 a1[4];
#pragma unroll
    for (int rt = 0; rt < 4; ++rt) a1[rt] = (floatx4){0.f, 0.f, 0.f, 0.f};
#pragma unroll
    for (int ks = 0; ks < 4; ++ks)
#pragma unroll
      for (int rt = 0; rt < 4; ++rt) {
        short8 bf = *(const short8*)&xb[(rt * 16 + ln16) * 136 + ks * 32 + quad * 8];
        a1[rt] = MFMA_BF16(af[ks], bf, a1[rt]);
      }
    floatx4 bb = *(const floatx4*)&bq[nt * 16 + quad * 4];
#pragma unroll
    for (int rt = 0; rt < 4; ++rt) {
      short4v qv;
#pragma unroll
      for (int r = 0; r < 4; ++r) qv[r] = f2b(a1[rt][r] + bb[r]);
      *(short4v*)&qh[(rt * 16 + ln16) * 136 + nt * 16 + quad * 4] = qv;
    }
  }
  __syncthreads();

  // attn2: 256 threads; thread pair per (row, head). half = c-split.
  {
    const int row  = tid >> 2;
    const int hd   = (tid >> 1) & 1;
    const int half = tid & 1;
    const int t = t0 + row;
    const short* qrow = &qh[row * 136 + hd * 64];
    const float* kvh  = &kv[hd * 640];
    float p[10];
#pragma unroll
    for (int j = 0; j < 10; ++j) p[j] = 0.f;
#pragma unroll
    for (int ci = 0; ci < 4; ++ci) {
      const int c = half * 4 + ci;
      short8 qs = *(const short8*)&qrow[c * 8];
      float qf[8];
#pragma unroll
      for (int u = 0; u < 8; ++u) qf[u] = b2f(qs[u]);
#pragma unroll
      for (int j = 0; j < 10; ++j) {
        const float* kp = &kvh[j * 64 + c * 8];
        floatx4 k0 = *(const floatx4*)kp;
        floatx4 k1 = *(const floatx4*)(kp + 4);
        p[j] += qf[0] * k0[0] + qf[1] * k0[1] + qf[2] * k0[2] + qf[3] * k0[3]
              + qf[4] * k1[0] + qf[5] * k1[1] + qf[6] * k1[2] + qf[7] * k1[3];
      }
    }
#pragma unroll
    for (int j = 0; j < 10; ++j) p[j] += __shfl_xor(p[j], 1);
    const bool full = (t >= 10);
    const int jlo = t - 5, jhi = t + 5;
    float mx = -1e30f;
#pragma unroll
    for (int j = 0; j < 10; ++j) {
      float s = fminf(fmaxf(p[j] * 0.125f, -10000.0f), 10000.0f);
      s = (full || (j >= jlo && j <= jhi)) ? s : -1e30f;
      p[j] = s; mx = fmaxf(mx, s);
    }
    float den = 0.f;
#pragma unroll
    for (int j = 0; j < 10; ++j) { p[j] = __expf(p[j] - mx); den += p[j]; }
    const float rden = 1.0f / den;
#pragma unroll
    for (int j = 0; j < 10; ++j) p[j] *= rden;
#pragma unroll
    for (int ci = 0; ci < 8; ++ci) {
      const int c = half * 8 + ci;
      floatx4 o = {0.f, 0.f, 0.f, 0.f};
#pragma unroll
      for (int j = 0; j < 10; ++j) {
        floatx4 vv = *(const floatx4*)&kvh[j * 64 + c * 4];
        o += p[j] * vv;
      }
      short4v s;
#pragma unroll
      for (int r = 0; r < 4; ++r) s[r] = f2b(o[r]);
      *(short4v*)&xb[row * 136 + hd * 64 + c * 4] = s;
    }
  }
  __syncthreads();

  // MLP2, column-split (r7 form: af[4] per n, bf read per rt)
  floatx4 acc2[2][4];
#pragma unroll
  for (int n = 0; n < 2; ++n)
#pragma unroll
    for (int rt = 0; rt < 4; ++rt) acc2[n][rt] = (floatx4){0.f, 0.f, 0.f, 0.f};

#pragma unroll 1
  for (int qtr = 0; qtr < 4; ++qtr) {
#pragma unroll
    for (int n = 0; n < 2; ++n) {
      const int ntg = qtr * 8 + nt0 + n;
      short8 af[4];
#pragma unroll
      for (int ks = 0; ks < 4; ++ks)
        af[ks] = *(const short8*)&w1p[((ntg * 4 + ks) * 64 + lane) * 8];
      floatx4 a1[4];
#pragma unroll
      for (int rt = 0; rt < 4; ++rt) a1[rt] = (floatx4){0.f, 0.f, 0.f, 0.f};
#pragma unroll
      for (int ks = 0; ks < 4; ++ks)
#pragma unroll
        for (int rt = 0; rt < 4; ++rt) {
          short8 bf = *(const short8*)&xb[(rt * 16 + ln16) * 136 + ks * 32 + quad * 8];
          a1[rt] = MFMA_BF16(af[ks], bf, a1[rt]);
        }
      floatx4 bias = *(const floatx4*)&b1[ntg * 16 + quad * 4];
#pragma unroll
      for (int rt = 0; rt < 4; ++rt) {
        short4v hv;
#pragma unroll
        for (int r = 0; r < 4; ++r) hv[r] = f2b(gelu_fast(a1[rt][r] + bias[r]));
        *(short4v*)&qh[(rt * 16 + ln16) * 136 + (nt0 + n) * 16 + quad * 4] = hv;
      }
    }
    __syncthreads();
#pragma unroll
    for (int n = 0; n < 2; ++n) {
      const int nt = nt0 + n;
      short8 af[4];
#pragma unroll
      for (int ks = 0; ks < 4; ++ks)
        af[ks] = *(const short8*)&w2p[((nt * 16 + qtr * 4 + ks) * 64 + lane) * 8];
#pragma unroll
      for (int ks = 0; ks < 4; ++ks)
#pragma unroll
        for (int rt = 0; rt < 4; ++rt) {
          short8 bf = *(const short8*)&qh[(rt * 16 + ln16) * 136 + ks * 32 + quad * 8];
          acc2[n][rt] = MFMA_BF16(af[ks], bf, acc2[n][rt]);
        }
    }
    __syncthreads();
  }

  // ---- dual-LN epilogue via kv[] reuse (kv dead after attn phase) ----
  float* st = kv;          // st[0..255]=s1, st[256..511]=s2, [512..767]=z1, [768..1023]=z2
  float mean1r[4], rstd1r[4];

  // round 1: v = acc2 + b2 + residual(XPb, L2-resident); per-wave partials
#pragma unroll
  for (int rt = 0; rt < 4; ++rt) {
    const int tok = rt * 16 + ln16;
    float p1 = 0.f, p2 = 0.f;
#pragma unroll
    for (int n = 0; n < 2; ++n) {
      const int col = (nt0 + n) * 16 + quad * 4;
      floatx4 bb = *(const floatx4*)&b2[col];
      short4v xs4 = *(const short4v*)&XPb[basef + (long)tok * 4096 + col];
      floatx4 v;
#pragma unroll
      for (int r = 0; r < 4; ++r) {
        v[r] = acc2[n][rt][r] + bb[r] + b2f(xs4[r]);
        p1 += v[r]; p2 += v[r] * v[r];
      }
      acc2[n][rt] = v;
    }
    p1 += __shfl_xor(p1, 16); p1 += __shfl_xor(p1, 32);
    p2 += __shfl_xor(p2, 16); p2 += __shfl_xor(p2, 32);
    if (quad == 0) { st[tok * 4 + wave] = p1; st[256 + tok * 4 + wave] = p2; }
  }
  __syncthreads();

  // round 2: combine -> mean1/rstd1; z-partials -> st[512..]
#pragma unroll
  for (int rt = 0; rt < 4; ++rt) {
    const int tok = rt * 16 + ln16;
    float s1 = 0.f, s2 = 0.f;
#pragma unroll
    for (int w4 = 0; w4 < 4; ++w4) { s1 += st[tok * 4 + w4]; s2 += st[256 + tok * 4 + w4]; }
    const float mean1 = s1 * (1.0f / 128.0f);
    const float rstd1 = rsqrtf(s2 * (1.0f / 128.0f) - mean1 * mean1 + 1e-5f);
    mean1r[rt] = mean1; rstd1r[rt] = rstd1;
    float q1 = 0.f, q2 = 0.f;
#pragma unroll
    for (int n = 0; n < 2; ++n) {
      const int col = (nt0 + n) * 16 + quad * 4;
      floatx4 gg = *(const floatx4*)&g2[col];
      floatx4 bb = *(const floatx4*)&be2[col];
#pragma unroll
      for (int r = 0; r < 4; ++r) {
        float z = (acc2[n][rt][r] - mean1) * rstd1 * gg[r] + bb[r];
        q1 += z; q2 += z * z;
      }
    }
    q1 += __shfl_xor(q1, 16); q1 += __shfl_xor(q1, 32);
    q2 += __shfl_xor(q2, 16); q2 += __shfl_xor(q2, 32);
    if (quad == 0) { st[512 + tok * 4 + wave] = q1; st[768 + tok * 4 + wave] = q2; }
  }
  __syncthreads();

  // round 3: combine -> mean2/rstd2; final LN2+LN3 write
#pragma unroll
  for (int rt = 0; rt < 4; ++rt) {
    const int tok = rt * 16 + ln16;
    float s1 = 0.f, s2 = 0.f;
#pragma unroll
    for (int w4 = 0; w4 < 4; ++w4) { s1 += st[512 + tok * 4 + w4]; s2 += st[768 + tok * 4 + w4]; }
    const float mean2 = s1 * (1.0f / 128.0f);
    const float rstd2 = rsqrtf(s2 * (1.0f / 128.0f) - mean2 * mean2 + 1e-5f);
    const float mean1 = mean1r[rt], rstd1 = rstd1r[rt];
    float* orow = OUT + basef + (long)tok * 4096;
#pragma unroll
    for (int n = 0; n < 2; ++n) {
      const int col = (nt0 + n) * 16 + quad * 4;
      floatx4 gg2 = *(const floatx4*)&g2[col];
      floatx4 bb2 = *(const floatx4*)&be2[col];
      floatx4 gg3 = *(const floatx4*)&g3[col];
      floatx4 bb3 = *(const floatx4*)&be3[col];
      floatx4 o4;
#pragma unroll
      for (int r = 0; r < 4; ++r) {
        float z = (acc2[n][rt][r] - mean1) * rstd1 * gg2[r] + bb2[r];
        o4[r] = (z - mean2) * rstd2 * gg3[r] + bb3[r];
      }
      *(floatx4*)&orow[col] = o4;
    }
  }
}

// ---------------------------------------------------------------------------
extern "C" void kernel_launch(void* const* d_in, const int* in_sizes, int n_in,
                              void* d_out, int out_size, void* d_ws, size_t ws_size,
                              hipStream_t stream) {
  const float* x        = (const float*)d_in[0];
  const float* router   = (const float*)d_in[1];
  const float* w_router = (const float*)d_in[2];
  const float* b_router = (const float*)d_in[3];
  const float* w_k  = (const float*)d_in[4];
  const float* b_k  = (const float*)d_in[5];
  const float* w_v  = (const float*)d_in[6];
  const float* b_v  = (const float*)d_in[7];
  const float* w_q  = (const float*)d_in[8];
  const float* b_q  = (const float*)d_in[9];
  const float* m1w1 = (const float*)d_in[10];
  const float* m1b1 = (const float*)d_in[11];
  const float* m1w2 = (const float*)d_in[12];
  const float* m1b2 = (const float*)d_in[13];
  const float* m2w1 = (const float*)d_in[14];
  const float* m2b1 = (const float*)d_in[15];
  const float* m2w2 = (const float*)d_in[16];
  const float* m2b2 = (const float*)d_in[17];
  const float* g1  = (const float*)d_in[18];
  const float* be1 = (const float*)d_in[19];
  const float* g2  = (const float*)d_in[20];
  const float* be2 = (const float*)d_in[21];
  const float* g3  = (const float*)d_in[22];
  const float* be3 = (const float*)d_in[23];
  float* out = (float*)d_out;

  char* ws = (char*)d_ws;
  short* XPb = (short*)ws;                      // x_proj bf16: 32 MiB
  float* BUF = (float*)(ws + 33554432);         // 640 KiB
  short* w1p1 = (short*)(ws + 34209792);
  short* w2p1 = w1p1 + 65536;
  short* w1p2 = w2p1 + 65536;
  short* w2p2 = w1p2 + 65536;
  short* wqp  = w2p2 + 65536;
  short* wkp  = wqp + 16384;
  short* wvp  = wkp + 16384;
  short* wrp  = wvp + 16384;

  pack_all<<<1280, 256, 0, stream>>>(m1w1, m1w2, m2w1, m2w2, w_q, w_k, w_v, w_router,
                                     w1p1, w2p1, w1p2, w2p2, wqp, wkp, wvp, wrp);
  k_mlp_ln<<<2048, 256, 0, stream>>>(x, XPb, w1p1, m1b1, w2p1, m1b2, g1, be1);
  k_buffer<<<128, 256, 0, stream>>>(XPb, router, wkp, b_k, wvp, b_v, wrp, b_router, BUF);
  k_attn_mlp<<<2048, 256, 0, stream>>>(XPb, BUF, out, wqp, b_q,
                                       w1p2, m2b1, w2p2, m2b2,
                                       g2, be2, g3, be3);
}